// Round 1
// baseline (2019.603 us; speedup 1.0000x reference)
//
#include <hip/hip_runtime.h>

// RNN scan: h_{t+1} = 0.8*h_t + 0.2*(relu(h_t @ W_rec^T + b_rec + inp_t) + rn_t)
// 128 chains -> 128 blocks x 512 threads, thread n owns row n of W_rec (fp16).
//
// W row = 64 groups of 8 cols, split:
//   groups  0..39 -> 40 NAMED uint4 SSA values (160 VGPRs)
//   groups 40..46 -> LDS ltail[7][512] uint4 (57 KB, static-LDS cap is 64 KB)
//   groups 47..63 -> fp16 image in d_ws, streamed from L2 each step (272 B/thr/step)
//
// R4 THEORY: previous best (2009 us) measured VGPR_Count=128 despite naming
// 176 VGPRs of W -> the waves_per_eu(2,2) pin did NOT take; the backend
// budgeted from LDS-achievable occupancy (59 KB -> 2 blocks/CU -> 4 waves/EU
// -> 128 regs) and rematerialized the W loads into the loop: 1408 B/thread/step
// of fp32 W re-fetched from L2 (~3.1 TB/s per XCD, at the per-XCD ceiling)
// plus ~580 reconversion VALU insts/step. VALUBusy 39%, 61% stall.
// FIX: amdgpu_num_vgpr(256) -- LLVM consults "amdgpu-num-vgpr" BEFORE the
// occupancy-derived budget, unlike waves-per-eu. Also trim named groups
// 44 -> 40 so true need (~235 regs incl. in-flight streams) sits safely
// under 256 and no spill cascade starts.
// PREDICT: VGPR_Count -> 256, VALUBusy -> 60-80%, dur -> ~1 ms.
// WHY the asm "+v" barriers: makes each W component an opaque asm result so
// rematerialization of the global load is impossible.
//
// h broadcast: one ds_read_b128 per lane (lane l holds h[8l..8l+8]), then
// v_readlane with constant lane index feeds v_dot2_f32_f16's SGPR operand:
// zero LDS fan-out traffic (R0's per-thread LDS broadcast was LDS-BW bound).

#define B_  128
#define T_  512
#define N_  512
#define IN_ 6

#define NREGG  40                    // groups in VGPRs   (cols 0..320)
#define NLDSG  7                     // groups in LDS     (cols 320..376)
#define NWSG   17                    // groups from d_ws  (cols 376..512)
#define LDS_C0 (8 * NREGG)           // 320
#define WS_C0  (8 * (NREGG + NLDSG)) // 376

typedef _Float16 half2_t __attribute__((ext_vector_type(2)));

#if __has_builtin(__builtin_amdgcn_fdot2)
#define HAVE_FDOT2 1
#else
#define HAVE_FDOT2 0
#endif

__device__ __forceinline__ float dot2_acc(half2_t a, half2_t b, float c) {
#if HAVE_FDOT2
    return __builtin_amdgcn_fdot2(a, b, c, false);
#else
    c = fmaf((float)a[0], (float)b[0], c);
    c = fmaf((float)a[1], (float)b[1], c);
    return c;
#endif
}

__device__ __forceinline__ half2_t h2bits(unsigned s) {
    union { unsigned u; half2_t h; } cv; cv.u = s; return cv.h;
}

// 8 consecutive fp32 -> 8 packed fp16 in a uint4
__device__ __forceinline__ uint4 pack8(const float* __restrict__ p) {
    const float4 f0 = ((const float4*)p)[0];
    const float4 f1 = ((const float4*)p)[1];
    union { unsigned u[4]; half2_t h[4]; } cv;
    cv.h[0] = half2_t{(_Float16)f0.x, (_Float16)f0.y};
    cv.h[1] = half2_t{(_Float16)f0.z, (_Float16)f0.w};
    cv.h[2] = half2_t{(_Float16)f1.x, (_Float16)f1.y};
    cv.h[3] = half2_t{(_Float16)f1.z, (_Float16)f1.w};
    return uint4{cv.u[0], cv.u[1], cv.u[2], cv.u[3]};
}

// opaque redefinition: blocks rematerialization of the producing load
#define KEEP4(v) asm volatile("" : "+v"((v).x), "+v"((v).y), "+v"((v).z), "+v"((v).w))

// ---- prep: W_rec cols [WS_C0,512) -> fp16 image, layout [NWSG][N_] uint4 ----
__global__ void prep_tail_kernel(const float* __restrict__ Wrec,
                                 uint4* __restrict__ ws) {
    int tid = blockIdx.x * blockDim.x + threadIdx.x;
    if (tid >= NWSG * N_) return;
    int g = tid >> 9, n = tid & (N_ - 1);
    ws[(size_t)g * N_ + n] = pack8(Wrec + (size_t)n * N_ + WS_C0 + 8 * g);
}

template <bool USE_WS>
__device__ __forceinline__ uint4 gload(const uint4* __restrict__ wsn,
                                       const float* __restrict__ wrow_ws, int g) {
    if constexpr (USE_WS) return wsn[g * N_];
    else return pack8(wrow_ws + 8 * g);
}

// one 8-col group: 4 readlane-broadcast h pairs dotted into 4 accumulators
#define DOTG(W, G) do {                                                                    \
    a0 = dot2_acc(h2bits((W).x), h2bits((unsigned)__builtin_amdgcn_readlane(hx,(G))), a0); \
    a1 = dot2_acc(h2bits((W).y), h2bits((unsigned)__builtin_amdgcn_readlane(hy,(G))), a1); \
    a2 = dot2_acc(h2bits((W).z), h2bits((unsigned)__builtin_amdgcn_readlane(hz,(G))), a2); \
    a3 = dot2_acc(h2bits((W).w), h2bits((unsigned)__builtin_amdgcn_readlane(hw,(G))), a3); \
} while (0)

template <bool USE_WS>
__global__ __launch_bounds__(512)
__attribute__((amdgpu_waves_per_eu(2, 2), amdgpu_num_vgpr(256)))
void rnn_scan_kernel(
    const float* __restrict__ u,     // [B,T,IN]
    const float* __restrict__ unz,   // [B,T,IN]
    const float* __restrict__ rnz,   // [B,T,N]
    const float* __restrict__ Wrec,  // [N,N]
    const float* __restrict__ brec,  // [N]
    const float* __restrict__ Win,   // [N,IN]
    const uint4* __restrict__ ws,    // fp16 tail image [NWSG][N_]
    float* __restrict__ out)         // [B,T,N]
{
    const int b = blockIdx.x;
    const int n = threadIdx.x;
    const int lane = n & 63;

    __shared__ uint4 ltail[NLDSG][N_];               // 57344 B
    __shared__ __align__(16) _Float16 hbuf[2][N_];   // 2048 B

    const float* wrow = Wrec + (size_t)n * N_;

    // ---- one-time: groups 0..39 as 40 NAMED uint4 (160 VGPRs) ----
    uint4 w0  = pack8(wrow +   0); uint4 w1  = pack8(wrow +   8); uint4 w2  = pack8(wrow +  16); uint4 w3  = pack8(wrow +  24);
    uint4 w4  = pack8(wrow +  32); uint4 w5  = pack8(wrow +  40); uint4 w6  = pack8(wrow +  48); uint4 w7  = pack8(wrow +  56);
    uint4 w8  = pack8(wrow +  64); uint4 w9  = pack8(wrow +  72); uint4 w10 = pack8(wrow +  80); uint4 w11 = pack8(wrow +  88);
    uint4 w12 = pack8(wrow +  96); uint4 w13 = pack8(wrow + 104); uint4 w14 = pack8(wrow + 112); uint4 w15 = pack8(wrow + 120);
    uint4 w16 = pack8(wrow + 128); uint4 w17 = pack8(wrow + 136); uint4 w18 = pack8(wrow + 144); uint4 w19 = pack8(wrow + 152);
    uint4 w20 = pack8(wrow + 160); uint4 w21 = pack8(wrow + 168); uint4 w22 = pack8(wrow + 176); uint4 w23 = pack8(wrow + 184);
    uint4 w24 = pack8(wrow + 192); uint4 w25 = pack8(wrow + 200); uint4 w26 = pack8(wrow + 208); uint4 w27 = pack8(wrow + 216);
    uint4 w28 = pack8(wrow + 224); uint4 w29 = pack8(wrow + 232); uint4 w30 = pack8(wrow + 240); uint4 w31 = pack8(wrow + 248);
    uint4 w32 = pack8(wrow + 256); uint4 w33 = pack8(wrow + 264); uint4 w34 = pack8(wrow + 272); uint4 w35 = pack8(wrow + 280);
    uint4 w36 = pack8(wrow + 288); uint4 w37 = pack8(wrow + 296); uint4 w38 = pack8(wrow + 304); uint4 w39 = pack8(wrow + 312);

    KEEP4(w0);  KEEP4(w1);  KEEP4(w2);  KEEP4(w3);  KEEP4(w4);  KEEP4(w5);  KEEP4(w6);  KEEP4(w7);
    KEEP4(w8);  KEEP4(w9);  KEEP4(w10); KEEP4(w11); KEEP4(w12); KEEP4(w13); KEEP4(w14); KEEP4(w15);
    KEEP4(w16); KEEP4(w17); KEEP4(w18); KEEP4(w19); KEEP4(w20); KEEP4(w21); KEEP4(w22); KEEP4(w23);
    KEEP4(w24); KEEP4(w25); KEEP4(w26); KEEP4(w27); KEEP4(w28); KEEP4(w29); KEEP4(w30); KEEP4(w31);
    KEEP4(w32); KEEP4(w33); KEEP4(w34); KEEP4(w35); KEEP4(w36); KEEP4(w37); KEEP4(w38); KEEP4(w39);

    // ---- one-time: groups 40..46 into LDS ----
#pragma unroll
    for (int j = 0; j < NLDSG; ++j)
        ltail[j][n] = pack8(wrow + LDS_C0 + 8 * j);

    const float win0 = Win[n * IN_ + 0], win1 = Win[n * IN_ + 1], win2 = Win[n * IN_ + 2];
    const float win3 = Win[n * IN_ + 3], win4 = Win[n * IN_ + 4], win5 = Win[n * IN_ + 5];
    const float br = brec[n];
    const uint4* wsn = ws + n;
    const float* wrow_ws = wrow + WS_C0;

    const float NS = 0.6324555320336759f;  // sqrt(2/alpha * sigma^2)
    float h = 0.0f;

    float* ob = out + (size_t)b * T_ * N_;
    const float* rb = rnz + (size_t)b * T_ * N_;
    const float2* ubp = (const float2*)(u   + (size_t)b * T_ * IN_);
    const float2* nbp = (const float2*)(unz + (size_t)b * T_ * IN_);

    hbuf[0][n] = (_Float16)0.0f;

    // inp for t=0
    float2 cu0 = ubp[0], cu1 = ubp[1], cu2 = ubp[2];
    float2 cn0 = nbp[0], cn1 = nbp[1], cn2 = nbp[2];
    float inp_c = br;
    inp_c = fmaf(win0, fmaf(NS, cn0.x, cu0.x), inp_c);
    inp_c = fmaf(win1, fmaf(NS, cn0.y, cu0.y), inp_c);
    inp_c = fmaf(win2, fmaf(NS, cn1.x, cu1.x), inp_c);
    inp_c = fmaf(win3, fmaf(NS, cn1.y, cu1.y), inp_c);
    inp_c = fmaf(win4, fmaf(NS, cn2.x, cu2.x), inp_c);
    inp_c = fmaf(win5, fmaf(NS, cn2.y, cu2.y), inp_c);
    float rn_c = rb[n];
    __syncthreads();

#pragma unroll 1
    for (int t = 0; t < T_ - 1; ++t) {
        ob[(size_t)t * N_ + n] = h;   // states[t] (t=0: zeros)

        // this wave's copy of full h: lane l -> h[8l..8l+8]
        const uint4 hv = ((const uint4*)hbuf[t & 1])[lane];
        const int hx = (int)hv.x, hy = (int)hv.y, hz = (int)hv.z, hw = (int)hv.w;

        // stream batch A (ws groups 0..5 -> col groups 47..52)
        uint4 sa0 = gload<USE_WS>(wsn, wrow_ws, 0), sa1 = gload<USE_WS>(wsn, wrow_ws, 1);
        uint4 sa2 = gload<USE_WS>(wsn, wrow_ws, 2), sa3 = gload<USE_WS>(wsn, wrow_ws, 3);
        uint4 sa4 = gload<USE_WS>(wsn, wrow_ws, 4), sa5 = gload<USE_WS>(wsn, wrow_ws, 5);

        // prefetch t+1 inputs (consumed after the dots)
        const float rn_n = rb[(t + 1) * N_ + n];
        const float2 pu0 = ubp[(t + 1) * 3 + 0], pu1 = ubp[(t + 1) * 3 + 1], pu2 = ubp[(t + 1) * 3 + 2];
        const float2 pn0 = nbp[(t + 1) * 3 + 0], pn1 = nbp[(t + 1) * 3 + 1], pn2 = nbp[(t + 1) * 3 + 2];

        float a0 = inp_c, a1 = 0.0f, a2 = 0.0f, a3 = 0.0f;

        DOTG(w0, 0);   DOTG(w1, 1);   DOTG(w2, 2);   DOTG(w3, 3);
        DOTG(w4, 4);   DOTG(w5, 5);   DOTG(w6, 6);   DOTG(w7, 7);
        DOTG(w8, 8);   DOTG(w9, 9);   DOTG(w10, 10); DOTG(w11, 11);
        DOTG(w12, 12); DOTG(w13, 13); DOTG(w14, 14); DOTG(w15, 15);

        // stream batch B (ws groups 6..11 -> col groups 53..58)
        uint4 sb0 = gload<USE_WS>(wsn, wrow_ws, 6),  sb1 = gload<USE_WS>(wsn, wrow_ws, 7);
        uint4 sb2 = gload<USE_WS>(wsn, wrow_ws, 8),  sb3 = gload<USE_WS>(wsn, wrow_ws, 9);
        uint4 sb4 = gload<USE_WS>(wsn, wrow_ws, 10), sb5 = gload<USE_WS>(wsn, wrow_ws, 11);

        DOTG(w16, 16); DOTG(w17, 17); DOTG(w18, 18); DOTG(w19, 19);
        DOTG(w20, 20); DOTG(w21, 21); DOTG(w22, 22); DOTG(w23, 23);
        DOTG(w24, 24); DOTG(w25, 25); DOTG(w26, 26); DOTG(w27, 27);
        DOTG(w28, 28); DOTG(w29, 29); DOTG(w30, 30); DOTG(w31, 31);
        DOTG(sa0, 47); DOTG(sa1, 48); DOTG(sa2, 49); DOTG(sa3, 50);
        DOTG(sa4, 51); DOTG(sa5, 52);

        // stream batch C (ws groups 12..16 -> col groups 59..63)
        uint4 sc0 = gload<USE_WS>(wsn, wrow_ws, 12), sc1 = gload<USE_WS>(wsn, wrow_ws, 13);
        uint4 sc2 = gload<USE_WS>(wsn, wrow_ws, 14), sc3 = gload<USE_WS>(wsn, wrow_ws, 15);
        uint4 sc4 = gload<USE_WS>(wsn, wrow_ws, 16);

        // LDS batch (issued early so lgkmcnt is hidden under the sb dots)
        uint4 la0 = ltail[0][n], la1 = ltail[1][n], la2 = ltail[2][n], la3 = ltail[3][n];
        uint4 lb0 = ltail[4][n], lb1 = ltail[5][n], lb2 = ltail[6][n];

        DOTG(w32, 32); DOTG(w33, 33); DOTG(w34, 34); DOTG(w35, 35);
        DOTG(w36, 36); DOTG(w37, 37); DOTG(w38, 38); DOTG(w39, 39);
        DOTG(sb0, 53); DOTG(sb1, 54); DOTG(sb2, 55); DOTG(sb3, 56);
        DOTG(sb4, 57); DOTG(sb5, 58);

        DOTG(la0, 40); DOTG(la1, 41); DOTG(la2, 42); DOTG(la3, 43);
        DOTG(lb0, 44); DOTG(lb1, 45); DOTG(lb2, 46);
        DOTG(sc0, 59); DOTG(sc1, 60); DOTG(sc2, 61); DOTG(sc3, 62);
        DOTG(sc4, 63);

        const float pre = (a0 + a1) + (a2 + a3);
        h = 0.8f * h + 0.2f * (fmaxf(pre, 0.0f) + rn_c);
        hbuf[(t + 1) & 1][n] = (_Float16)h;

        float inp_n = br;
        inp_n = fmaf(win0, fmaf(NS, pn0.x, pu0.x), inp_n);
        inp_n = fmaf(win1, fmaf(NS, pn0.y, pu0.y), inp_n);
        inp_n = fmaf(win2, fmaf(NS, pn1.x, pu1.x), inp_n);
        inp_n = fmaf(win3, fmaf(NS, pn1.y, pu1.y), inp_n);
        inp_n = fmaf(win4, fmaf(NS, pn2.x, pu2.x), inp_n);
        inp_n = fmaf(win5, fmaf(NS, pn2.y, pu2.y), inp_n);
        inp_c = inp_n;
        rn_c  = rn_n;
        __syncthreads();
    }
    ob[(size_t)(T_ - 1) * N_ + n] = h;  // states[511]
}

extern "C" void kernel_launch(void* const* d_in, const int* in_sizes, int n_in,
                              void* d_out, int out_size, void* d_ws, size_t ws_size,
                              hipStream_t stream) {
    const float* u    = (const float*)d_in[0];
    const float* unz  = (const float*)d_in[1];
    const float* rnz  = (const float*)d_in[2];
    const float* Wrec = (const float*)d_in[3];
    const float* brec = (const float*)d_in[4];
    const float* Win  = (const float*)d_in[5];
    float* out = (float*)d_out;

    const size_t ws_need = (size_t)NWSG * N_ * sizeof(uint4);  // 139264 B
    if (ws_size >= ws_need) {
        uint4* ws = (uint4*)d_ws;
        prep_tail_kernel<<<(NWSG * N_ + 255) / 256, 256, 0, stream>>>(Wrec, ws);
        rnn_scan_kernel<true><<<dim3(B_), dim3(N_), 0, stream>>>(
            u, unz, rnz, Wrec, brec, Win, ws, out);
    } else {
        rnn_scan_kernel<false><<<dim3(B_), dim3(N_), 0, stream>>>(
            u, unz, rnz, Wrec, brec, Win, nullptr, out);
    }
}

// Round 2
// 1331.282 us; speedup vs baseline: 1.5170x; 1.5170x over previous
//
#include <hip/hip_runtime.h>

// RNN scan: h_{t+1} = 0.8*h_t + 0.2*(relu(h_t @ W_rec^T + b_rec + inp_t) + rn_t)
// 128 chains -> 128 blocks x 512 threads, thread n owns row n of W_rec (fp16).
//
// W row = 64 groups of 8 cols, split:
//   groups  0..39 -> 40 NAMED uint4 SSA values (160 VGPRs)
//   groups 40..54 -> LDS ltail[15][512] uint4 (122.9 KB static)
//   groups 55..63 -> fp16 image in d_ws, streamed from L2 each step (144 B/thr/step)
//
// R5 THEORY: R4 showed VGPR_Count=128 with BOTH amdgpu_waves_per_eu(2,2) and
// amdgpu_num_vgpr(256) present -> the attributes are overridden by the
// backend's LDS-occupancy clamp: 59 KB static LDS -> 2 blocks/CU achievable
// -> 4 waves/EU -> budget 512/4 = 128 regs, and the allocator spills ~100
// regs to (L2-resident, FETCH-invisible) scratch every step. Fix: raise
// static LDS past 80 KB so the heuristic ITSELF concludes 1 block/CU ->
// 2 waves/EU -> budget 256. This wastes nothing: runtime occupancy is
// already 1 block/CU (128 blocks on 256 CUs). Bonus: LDS now carries 15
// groups instead of 7, cutting the per-step L2 stream 272 -> 144 B/thread.
// gfx950 static LDS cap is 160 KB (learn_hip m201 uses 128 KiB static).
// PREDICT: VGPR_Count -> ~240-256, VALUBusy -> 70-90%, dur -> 550-800 us.
// WHY the asm "+v" barriers: makes each W component an opaque asm result so
// rematerialization of the producing load is impossible.
//
// h broadcast: one ds_read_b128 per lane (lane l holds h[8l..8l+8]), then
// v_readlane with constant lane index feeds v_dot2_f32_f16's SGPR operand:
// zero LDS fan-out traffic.

#define B_  128
#define T_  512
#define N_  512
#define IN_ 6

#define NREGG  40                    // groups in VGPRs   (cols 0..320)
#define NLDSG  15                    // groups in LDS     (cols 320..440)
#define NWSG   9                     // groups from d_ws  (cols 440..512)
#define LDS_C0 (8 * NREGG)           // 320
#define WS_C0  (8 * (NREGG + NLDSG)) // 440

typedef _Float16 half2_t __attribute__((ext_vector_type(2)));

#if __has_builtin(__builtin_amdgcn_fdot2)
#define HAVE_FDOT2 1
#else
#define HAVE_FDOT2 0
#endif

__device__ __forceinline__ float dot2_acc(half2_t a, half2_t b, float c) {
#if HAVE_FDOT2
    return __builtin_amdgcn_fdot2(a, b, c, false);
#else
    c = fmaf((float)a[0], (float)b[0], c);
    c = fmaf((float)a[1], (float)b[1], c);
    return c;
#endif
}

__device__ __forceinline__ half2_t h2bits(unsigned s) {
    union { unsigned u; half2_t h; } cv; cv.u = s; return cv.h;
}

// 8 consecutive fp32 -> 8 packed fp16 in a uint4
__device__ __forceinline__ uint4 pack8(const float* __restrict__ p) {
    const float4 f0 = ((const float4*)p)[0];
    const float4 f1 = ((const float4*)p)[1];
    union { unsigned u[4]; half2_t h[4]; } cv;
    cv.h[0] = half2_t{(_Float16)f0.x, (_Float16)f0.y};
    cv.h[1] = half2_t{(_Float16)f0.z, (_Float16)f0.w};
    cv.h[2] = half2_t{(_Float16)f1.x, (_Float16)f1.y};
    cv.h[3] = half2_t{(_Float16)f1.z, (_Float16)f1.w};
    return uint4{cv.u[0], cv.u[1], cv.u[2], cv.u[3]};
}

// opaque redefinition: blocks rematerialization of the producing load
#define KEEP4(v) asm volatile("" : "+v"((v).x), "+v"((v).y), "+v"((v).z), "+v"((v).w))

// ---- prep: W_rec cols [WS_C0,512) -> fp16 image, layout [NWSG][N_] uint4 ----
__global__ void prep_tail_kernel(const float* __restrict__ Wrec,
                                 uint4* __restrict__ ws) {
    int tid = blockIdx.x * blockDim.x + threadIdx.x;
    if (tid >= NWSG * N_) return;
    int g = tid >> 9, n = tid & (N_ - 1);
    ws[(size_t)g * N_ + n] = pack8(Wrec + (size_t)n * N_ + WS_C0 + 8 * g);
}

template <bool USE_WS>
__device__ __forceinline__ uint4 gload(const uint4* __restrict__ wsn,
                                       const float* __restrict__ wrow_ws, int g) {
    if constexpr (USE_WS) return wsn[g * N_];
    else return pack8(wrow_ws + 8 * g);
}

// one 8-col group: 4 readlane-broadcast h pairs dotted into 4 accumulators
#define DOTG(W, G) do {                                                                    \
    a0 = dot2_acc(h2bits((W).x), h2bits((unsigned)__builtin_amdgcn_readlane(hx,(G))), a0); \
    a1 = dot2_acc(h2bits((W).y), h2bits((unsigned)__builtin_amdgcn_readlane(hy,(G))), a1); \
    a2 = dot2_acc(h2bits((W).z), h2bits((unsigned)__builtin_amdgcn_readlane(hz,(G))), a2); \
    a3 = dot2_acc(h2bits((W).w), h2bits((unsigned)__builtin_amdgcn_readlane(hw,(G))), a3); \
} while (0)

template <bool USE_WS>
__global__ __launch_bounds__(512, 2)
void rnn_scan_kernel(
    const float* __restrict__ u,     // [B,T,IN]
    const float* __restrict__ unz,   // [B,T,IN]
    const float* __restrict__ rnz,   // [B,T,N]
    const float* __restrict__ Wrec,  // [N,N]
    const float* __restrict__ brec,  // [N]
    const float* __restrict__ Win,   // [N,IN]
    const uint4* __restrict__ ws,    // fp16 tail image [NWSG][N_]
    float* __restrict__ out)         // [B,T,N]
{
    const int b = blockIdx.x;
    const int n = threadIdx.x;
    const int lane = n & 63;

    __shared__ uint4 ltail[NLDSG][N_];               // 122880 B
    __shared__ __align__(16) _Float16 hbuf[2][N_];   // 2048 B

    const float* wrow = Wrec + (size_t)n * N_;

    // ---- one-time: groups 0..39 as 40 NAMED uint4 (160 VGPRs) ----
    uint4 w0  = pack8(wrow +   0); uint4 w1  = pack8(wrow +   8); uint4 w2  = pack8(wrow +  16); uint4 w3  = pack8(wrow +  24);
    uint4 w4  = pack8(wrow +  32); uint4 w5  = pack8(wrow +  40); uint4 w6  = pack8(wrow +  48); uint4 w7  = pack8(wrow +  56);
    uint4 w8  = pack8(wrow +  64); uint4 w9  = pack8(wrow +  72); uint4 w10 = pack8(wrow +  80); uint4 w11 = pack8(wrow +  88);
    uint4 w12 = pack8(wrow +  96); uint4 w13 = pack8(wrow + 104); uint4 w14 = pack8(wrow + 112); uint4 w15 = pack8(wrow + 120);
    uint4 w16 = pack8(wrow + 128); uint4 w17 = pack8(wrow + 136); uint4 w18 = pack8(wrow + 144); uint4 w19 = pack8(wrow + 152);
    uint4 w20 = pack8(wrow + 160); uint4 w21 = pack8(wrow + 168); uint4 w22 = pack8(wrow + 176); uint4 w23 = pack8(wrow + 184);
    uint4 w24 = pack8(wrow + 192); uint4 w25 = pack8(wrow + 200); uint4 w26 = pack8(wrow + 208); uint4 w27 = pack8(wrow + 216);
    uint4 w28 = pack8(wrow + 224); uint4 w29 = pack8(wrow + 232); uint4 w30 = pack8(wrow + 240); uint4 w31 = pack8(wrow + 248);
    uint4 w32 = pack8(wrow + 256); uint4 w33 = pack8(wrow + 264); uint4 w34 = pack8(wrow + 272); uint4 w35 = pack8(wrow + 280);
    uint4 w36 = pack8(wrow + 288); uint4 w37 = pack8(wrow + 296); uint4 w38 = pack8(wrow + 304); uint4 w39 = pack8(wrow + 312);

    KEEP4(w0);  KEEP4(w1);  KEEP4(w2);  KEEP4(w3);  KEEP4(w4);  KEEP4(w5);  KEEP4(w6);  KEEP4(w7);
    KEEP4(w8);  KEEP4(w9);  KEEP4(w10); KEEP4(w11); KEEP4(w12); KEEP4(w13); KEEP4(w14); KEEP4(w15);
    KEEP4(w16); KEEP4(w17); KEEP4(w18); KEEP4(w19); KEEP4(w20); KEEP4(w21); KEEP4(w22); KEEP4(w23);
    KEEP4(w24); KEEP4(w25); KEEP4(w26); KEEP4(w27); KEEP4(w28); KEEP4(w29); KEEP4(w30); KEEP4(w31);
    KEEP4(w32); KEEP4(w33); KEEP4(w34); KEEP4(w35); KEEP4(w36); KEEP4(w37); KEEP4(w38); KEEP4(w39);

    // ---- one-time: groups 40..54 into LDS ----
#pragma unroll
    for (int j = 0; j < NLDSG; ++j)
        ltail[j][n] = pack8(wrow + LDS_C0 + 8 * j);

    const float win0 = Win[n * IN_ + 0], win1 = Win[n * IN_ + 1], win2 = Win[n * IN_ + 2];
    const float win3 = Win[n * IN_ + 3], win4 = Win[n * IN_ + 4], win5 = Win[n * IN_ + 5];
    const float br = brec[n];
    const uint4* wsn = ws + n;
    const float* wrow_ws = wrow + WS_C0;

    const float NS = 0.6324555320336759f;  // sqrt(2/alpha * sigma^2)
    float h = 0.0f;

    float* ob = out + (size_t)b * T_ * N_;
    const float* rb = rnz + (size_t)b * T_ * N_;
    const float2* ubp = (const float2*)(u   + (size_t)b * T_ * IN_);
    const float2* nbp = (const float2*)(unz + (size_t)b * T_ * IN_);

    hbuf[0][n] = (_Float16)0.0f;

    // inp for t=0
    float2 cu0 = ubp[0], cu1 = ubp[1], cu2 = ubp[2];
    float2 cn0 = nbp[0], cn1 = nbp[1], cn2 = nbp[2];
    float inp_c = br;
    inp_c = fmaf(win0, fmaf(NS, cn0.x, cu0.x), inp_c);
    inp_c = fmaf(win1, fmaf(NS, cn0.y, cu0.y), inp_c);
    inp_c = fmaf(win2, fmaf(NS, cn1.x, cu1.x), inp_c);
    inp_c = fmaf(win3, fmaf(NS, cn1.y, cu1.y), inp_c);
    inp_c = fmaf(win4, fmaf(NS, cn2.x, cu2.x), inp_c);
    inp_c = fmaf(win5, fmaf(NS, cn2.y, cu2.y), inp_c);
    float rn_c = rb[n];
    __syncthreads();

#pragma unroll 1
    for (int t = 0; t < T_ - 1; ++t) {
        ob[(size_t)t * N_ + n] = h;   // states[t] (t=0: zeros)

        // this wave's copy of full h: lane l -> h[8l..8l+8]
        const uint4 hv = ((const uint4*)hbuf[t & 1])[lane];
        const int hx = (int)hv.x, hy = (int)hv.y, hz = (int)hv.z, hw = (int)hv.w;

        // stream batch A (ws groups 0..4 -> col groups 55..59)
        uint4 sa0 = gload<USE_WS>(wsn, wrow_ws, 0), sa1 = gload<USE_WS>(wsn, wrow_ws, 1);
        uint4 sa2 = gload<USE_WS>(wsn, wrow_ws, 2), sa3 = gload<USE_WS>(wsn, wrow_ws, 3);
        uint4 sa4 = gload<USE_WS>(wsn, wrow_ws, 4);

        // prefetch t+1 inputs (consumed after the dots)
        const float rn_n = rb[(t + 1) * N_ + n];
        const float2 pu0 = ubp[(t + 1) * 3 + 0], pu1 = ubp[(t + 1) * 3 + 1], pu2 = ubp[(t + 1) * 3 + 2];
        const float2 pn0 = nbp[(t + 1) * 3 + 0], pn1 = nbp[(t + 1) * 3 + 1], pn2 = nbp[(t + 1) * 3 + 2];

        float a0 = inp_c, a1 = 0.0f, a2 = 0.0f, a3 = 0.0f;

        DOTG(w0, 0);   DOTG(w1, 1);   DOTG(w2, 2);   DOTG(w3, 3);
        DOTG(w4, 4);   DOTG(w5, 5);   DOTG(w6, 6);   DOTG(w7, 7);
        DOTG(w8, 8);   DOTG(w9, 9);   DOTG(w10, 10); DOTG(w11, 11);
        DOTG(w12, 12); DOTG(w13, 13); DOTG(w14, 14); DOTG(w15, 15);

        // stream batch B (ws groups 5..8 -> col groups 60..63)
        uint4 sb0 = gload<USE_WS>(wsn, wrow_ws, 5), sb1 = gload<USE_WS>(wsn, wrow_ws, 6);
        uint4 sb2 = gload<USE_WS>(wsn, wrow_ws, 7), sb3 = gload<USE_WS>(wsn, wrow_ws, 8);

        DOTG(w16, 16); DOTG(w17, 17); DOTG(w18, 18); DOTG(w19, 19);
        DOTG(w20, 20); DOTG(w21, 21); DOTG(w22, 22); DOTG(w23, 23);
        DOTG(sa0, 55); DOTG(sa1, 56); DOTG(sa2, 57); DOTG(sa3, 58); DOTG(sa4, 59);

        // LDS batch 1 (groups 40..44)
        uint4 la0 = ltail[0][n], la1 = ltail[1][n], la2 = ltail[2][n], la3 = ltail[3][n], la4 = ltail[4][n];

        DOTG(w24, 24); DOTG(w25, 25); DOTG(w26, 26); DOTG(w27, 27);
        DOTG(w28, 28); DOTG(w29, 29); DOTG(w30, 30); DOTG(w31, 31);
        DOTG(sb0, 60); DOTG(sb1, 61); DOTG(sb2, 62); DOTG(sb3, 63);

        // LDS batch 2 (groups 45..49)
        uint4 lb0 = ltail[5][n], lb1 = ltail[6][n], lb2 = ltail[7][n], lb3 = ltail[8][n], lb4 = ltail[9][n];

        DOTG(w32, 32); DOTG(w33, 33); DOTG(w34, 34); DOTG(w35, 35);
        DOTG(w36, 36); DOTG(w37, 37); DOTG(w38, 38); DOTG(w39, 39);
        DOTG(la0, 40); DOTG(la1, 41); DOTG(la2, 42); DOTG(la3, 43); DOTG(la4, 44);

        // LDS batch 3 (groups 50..54)
        uint4 lc0 = ltail[10][n], lc1 = ltail[11][n], lc2 = ltail[12][n], lc3 = ltail[13][n], lc4 = ltail[14][n];

        DOTG(lb0, 45); DOTG(lb1, 46); DOTG(lb2, 47); DOTG(lb3, 48); DOTG(lb4, 49);
        DOTG(lc0, 50); DOTG(lc1, 51); DOTG(lc2, 52); DOTG(lc3, 53); DOTG(lc4, 54);

        const float pre = (a0 + a1) + (a2 + a3);
        h = 0.8f * h + 0.2f * (fmaxf(pre, 0.0f) + rn_c);
        hbuf[(t + 1) & 1][n] = (_Float16)h;

        float inp_n = br;
        inp_n = fmaf(win0, fmaf(NS, pn0.x, pu0.x), inp_n);
        inp_n = fmaf(win1, fmaf(NS, pn0.y, pu0.y), inp_n);
        inp_n = fmaf(win2, fmaf(NS, pn1.x, pu1.x), inp_n);
        inp_n = fmaf(win3, fmaf(NS, pn1.y, pu1.y), inp_n);
        inp_n = fmaf(win4, fmaf(NS, pn2.x, pu2.x), inp_n);
        inp_n = fmaf(win5, fmaf(NS, pn2.y, pu2.y), inp_n);
        inp_c = inp_n;
        rn_c  = rn_n;
        __syncthreads();
    }
    ob[(size_t)(T_ - 1) * N_ + n] = h;  // states[511]
}

extern "C" void kernel_launch(void* const* d_in, const int* in_sizes, int n_in,
                              void* d_out, int out_size, void* d_ws, size_t ws_size,
                              hipStream_t stream) {
    const float* u    = (const float*)d_in[0];
    const float* unz  = (const float*)d_in[1];
    const float* rnz  = (const float*)d_in[2];
    const float* Wrec = (const float*)d_in[3];
    const float* brec = (const float*)d_in[4];
    const float* Win  = (const float*)d_in[5];
    float* out = (float*)d_out;

    const size_t ws_need = (size_t)NWSG * N_ * sizeof(uint4);  // 73728 B
    if (ws_size >= ws_need) {
        uint4* ws = (uint4*)d_ws;
        prep_tail_kernel<<<(NWSG * N_ + 255) / 256, 256, 0, stream>>>(Wrec, ws);
        rnn_scan_kernel<true><<<dim3(B_), dim3(N_), 0, stream>>>(
            u, unz, rnz, Wrec, brec, Win, ws, out);
    } else {
        rnn_scan_kernel<false><<<dim3(B_), dim3(N_), 0, stream>>>(
            u, unz, rnz, Wrec, brec, Win, nullptr, out);
    }
}